// Round 2
// baseline (167.099 us; speedup 1.0000x reference)
//
#include <hip/hip_runtime.h>
#include <float.h>
#include <stdint.h>

#define EMB_DIM  300
#define MAX_LEN  128
#define HIDDEN   1000
#define NCLS     5
#define VOCAB_SZ 50000
#define KPAD     640     // 600 padded to 10*64
#define NPAD     1024    // 1000 padded to 16*64

typedef float    f32x4   __attribute__((ext_vector_type(4)));
typedef __bf16   bf16x8  __attribute__((ext_vector_type(8)));

__device__ __forceinline__ unsigned short f2bf(float f) {
    union { float f; uint32_t u; } v; v.f = f;
    uint32_t u = v.u;
    return (unsigned short)((u + 0x7FFFu + ((u >> 16) & 1u)) >> 16);   // RNE
}
__device__ __forceinline__ float bf2f(unsigned short h) {
    union { uint32_t u; float f; } v; v.u = ((uint32_t)h) << 16;
    return v.f;
}

// ---------------------------------------------------------------------------
// fused_prep_pool: ONE dispatch for everything upstream of the GEMM.
//  blocks [0, poolBlocks):            pool 2 batch rows/block from f32 emb
//  blocks [poolBlocks, +640):         transpose W1 -> W1T bf16 [1024][640]
//  blocks [poolBlocks+640, +20):      W2 -> W2T bf16 [5][1024]
//  blocks [poolBlocks+660, +outBlks): out[m][c] = b2[c]  (gemm1p atomic-adds)
// Pool and weight-prep are independent -> they overlap inside one dispatch.
// No bf16 emb table: per-call conversion (60 MB rd + 32 MB wr) cost more
// than it saved on the (L3-resident) gather.
// ---------------------------------------------------------------------------
__global__ __launch_bounds__(256) void fused_prep_pool(
    const int* __restrict__ x, const int* __restrict__ lengths,
    const float* __restrict__ emb,
    const float* __restrict__ W1, unsigned short* __restrict__ Bt,
    const float* __restrict__ W2, unsigned short* __restrict__ W2t,
    const float* __restrict__ b2, float* __restrict__ out,
    unsigned short* __restrict__ rep,
    int M, int poolBlocks)
{
    __shared__ float tsh[32][33];        // W1 transpose scratch
    __shared__ int   sidx[2][MAX_LEN];   // pool indices (2 rows/block)
    const int blk = blockIdx.x;
    const int tid = threadIdx.x;

    if (blk < poolBlocks) {
        // ---------------- pool: 2 batch rows per 256-thread block ----------
        const int half = tid >> 7;             // 0 / 1
        const int t    = tid & 127;
        const int b    = blk * 2 + half;
        {
            int v = x[b * MAX_LEN + t];
            sidx[half][t] = max(0, min(v, VOCAB_SZ - 1));
        }
        __syncthreads();

        unsigned short* rb = rep + (size_t)b * KPAD;

        if (t >= 75) {
            if (t < 85) {                      // zero pad cols 600..639
                ushort4 z = {0, 0, 0, 0};
                *(ushort4*)(rb + 600 + (t - 75) * 4) = z;
            }
            return;
        }

        int L = lengths[b];
        L = max(1, min(L, MAX_LEN));

        const int d = t * 4;                   // dims [d, d+4)
        const float* base = emb + d;
        const int* si = sidx[half];
        float4 s  = {0.f, 0.f, 0.f, 0.f};
        float4 mx = {-FLT_MAX, -FLT_MAX, -FLT_MAX, -FLT_MAX};

        int i = 0;
        for (; i + 4 <= L; i += 4) {           // 4 loads in flight
            const float4 a = *(const float4*)(base + (size_t)si[i]     * EMB_DIM);
            const float4 c = *(const float4*)(base + (size_t)si[i + 1] * EMB_DIM);
            const float4 e = *(const float4*)(base + (size_t)si[i + 2] * EMB_DIM);
            const float4 g = *(const float4*)(base + (size_t)si[i + 3] * EMB_DIM);
            s.x += (a.x + c.x) + (e.x + g.x);
            s.y += (a.y + c.y) + (e.y + g.y);
            s.z += (a.z + c.z) + (e.z + g.z);
            s.w += (a.w + c.w) + (e.w + g.w);
            mx.x = fmaxf(mx.x, fmaxf(fmaxf(a.x, c.x), fmaxf(e.x, g.x)));
            mx.y = fmaxf(mx.y, fmaxf(fmaxf(a.y, c.y), fmaxf(e.y, g.y)));
            mx.z = fmaxf(mx.z, fmaxf(fmaxf(a.z, c.z), fmaxf(e.z, g.z)));
            mx.w = fmaxf(mx.w, fmaxf(fmaxf(a.w, c.w), fmaxf(e.w, g.w)));
        }
        for (; i < L; ++i) {
            const float4 a = *(const float4*)(base + (size_t)si[i] * EMB_DIM);
            s.x += a.x; s.y += a.y; s.z += a.z; s.w += a.w;
            mx.x = fmaxf(mx.x, a.x); mx.y = fmaxf(mx.y, a.y);
            mx.z = fmaxf(mx.z, a.z); mx.w = fmaxf(mx.w, a.w);
        }

        const float inv = 1.0f / (float)L;
        ushort4 av, mv;
        av.x = f2bf(s.x * inv); av.y = f2bf(s.y * inv);
        av.z = f2bf(s.z * inv); av.w = f2bf(s.w * inv);
        mv.x = f2bf(mx.x); mv.y = f2bf(mx.y); mv.z = f2bf(mx.z); mv.w = f2bf(mx.w);
        *(ushort4*)(rb + d)       = av;        // avg -> [0,300)
        *(ushort4*)(rb + 300 + d) = mv;        // max -> [300,600)
        return;
    }

    const int pb = blk - poolBlocks;
    if (pb < 640) {
        // ---------------- W1 transpose: pb -> (px, py) in (32, 20) ----------
        const int px = pb & 31, py = pb >> 5;
        const int tx = tid & 31, ty = tid >> 5;        // 32 x 8
        const int n0 = px * 32, k0 = py * 32;
        #pragma unroll
        for (int i = 0; i < 4; ++i) {
            int k = k0 + ty + i * 8, n = n0 + tx;
            tsh[ty + i * 8][tx] = (k < 600 && n < HIDDEN) ? W1[(size_t)k * HIDDEN + n] : 0.f;
        }
        __syncthreads();
        #pragma unroll
        for (int i = 0; i < 4; ++i) {
            int n = n0 + ty + i * 8, k = k0 + tx;
            Bt[(size_t)n * KPAD + k] = f2bf(tsh[tx][ty + i * 8]);
        }
        return;
    }
    const int pc = pb - 640;
    if (pc < 20) {                                     // W2T: 20 blocks
        const int i = pc * 256 + tid;                  // [0, 5120)
        const int c = i >> 10, k = i & 1023;
        const float v = (k < HIDDEN) ? W2[(size_t)k * NCLS + c] : 0.f;
        W2t[(size_t)c * 1024 + k] = f2bf(v);
        return;
    }
    const int po = pc - 20;                            // out init = b2
    const int oi = po * 256 + tid;
    if (oi < M * NCLS) out[oi] = b2[oi % NCLS];
}

// ---------------------------------------------------------------------------
// gemm1p: out[m][c] += sum over this block's n-slice of relu(rep@W1+b1)@W2.
// 128x128 tile, BK=64 (10 K-iters), m97 geometry: 4 waves, 64x64/wave,
// 4x4 16x16x32 frags, LDS 64KB dbuf, global_load_lds(16B).
// Fused epilogue: relu + W2, 16-lane butterfly over n, cross-wave combine
// in LDS, atomicAdd into out (pre-initialized to b2 by fused_prep_pool).
// ---------------------------------------------------------------------------
#define BM 128
#define BN 128
#define BK 64

__global__ __launch_bounds__(256, 2) void gemm1p(
    const unsigned short* __restrict__ A,    // rep  [M][640] bf16
    const unsigned short* __restrict__ Bt,   // W1T  [1024][640] bf16
    const float* __restrict__ bias,          // b1 [1000]
    const unsigned short* __restrict__ W2t,  // [5][1024] bf16
    float* __restrict__ out,                 // [M][5] f32, pre-init to b2
    int M)
{
    __shared__ unsigned short As[2][BM * BK];   // 16 KB per buffer
    __shared__ unsigned short Bs[2][BN * BK];

    const int tid  = threadIdx.x;
    const int wv   = tid >> 6;
    const int lane = tid & 63;
    const int bm   = blockIdx.y * BM;
    const int bn   = blockIdx.x * BN;
    const int wr   = (wv & 1) * 64;
    const int wc   = (wv >> 1) * 64;

    f32x4 acc[4][4] = {};

    auto stage = [&](int buf, int k0) {
        // each tile: 128 rows x 128 B = 1024 16B-chunks -> 4 instr/wave/matrix
        #pragma unroll
        for (int j = 0; j < 4; ++j) {
            const int ci  = (wv * 4 + j) * 64 + lane;
            const int row = ci >> 3, c = ci & 7;
            __builtin_amdgcn_global_load_lds(
                A + (size_t)(bm + row) * KPAD + k0 + c * 8,
                &As[buf][(wv * 4 + j) * 512], 16, 0, 0);
        }
        #pragma unroll
        for (int j = 0; j < 4; ++j) {
            const int ci  = (wv * 4 + j) * 64 + lane;
            const int row = ci >> 3, c = ci & 7;
            __builtin_amdgcn_global_load_lds(
                Bt + (size_t)(bn + row) * KPAD + k0 + c * 8,
                &Bs[buf][(wv * 4 + j) * 512], 16, 0, 0);
        }
    };

    stage(0, 0);
    int cur = 0;
    const int q = lane >> 4, r16 = lane & 15;

    #pragma unroll 1
    for (int it = 0; it < KPAD / BK; ++it) {
        __syncthreads();                           // drains prev stage (vmcnt 0)
        if (it + 1 < KPAD / BK) stage(cur ^ 1, (it + 1) * BK);

        #pragma unroll
        for (int ks = 0; ks < BK; ks += 32) {
            bf16x8 af[4], bfr[4];
            #pragma unroll
            for (int mi = 0; mi < 4; ++mi)
                af[mi] = *(const bf16x8*)&As[cur][(wr + mi * 16 + r16) * BK + ks + q * 8];
            #pragma unroll
            for (int nj = 0; nj < 4; ++nj)
                bfr[nj] = *(const bf16x8*)&Bs[cur][(wc + nj * 16 + r16) * BK + ks + q * 8];
            #pragma unroll
            for (int mi = 0; mi < 4; ++mi)
                #pragma unroll
                for (int nj = 0; nj < 4; ++nj)
                    acc[mi][nj] = __builtin_amdgcn_mfma_f32_16x16x32_bf16(
                        af[mi], bfr[nj], acc[mi][nj], 0, 0, 0);
        }
        cur ^= 1;
    }

    // ---- fused epilogue: h -> partial logits ----
    // C/D layout: col(n) = r16, row(m) = q*4 + reg (+ mi*16).
    float bv[4], w2v[4][NCLS];
    #pragma unroll
    for (int nj = 0; nj < 4; ++nj) {
        const int n = bn + wc + nj * 16 + r16;
        if (n < HIDDEN) {
            bv[nj] = bias[n];
            #pragma unroll
            for (int c = 0; c < NCLS; ++c) w2v[nj][c] = bf2f(W2t[c * 1024 + n]);
        } else {
            bv[nj] = 0.f;
            #pragma unroll
            for (int c = 0; c < NCLS; ++c) w2v[nj][c] = 0.f;
        }
    }

    __syncthreads();                     // LDS reuse: As becomes float scratch
    float* pl = (float*)As;              // [4 waves][64 rows][5] = 5120 B

    #pragma unroll
    for (int mi = 0; mi < 4; ++mi) {
        #pragma unroll
        for (int r = 0; r < 4; ++r) {
            float p[NCLS] = {0.f, 0.f, 0.f, 0.f, 0.f};
            #pragma unroll
            for (int nj = 0; nj < 4; ++nj) {
                float h = fmaxf(acc[mi][nj][r] + bv[nj], 0.f);
                #pragma unroll
                for (int c = 0; c < NCLS; ++c) p[c] += h * w2v[nj][c];
            }
            #pragma unroll
            for (int off = 1; off < 16; off <<= 1)
                #pragma unroll
                for (int c = 0; c < NCLS; ++c)
                    p[c] += __shfl_xor(p[c], off, 64);
            if (r16 == 0) {
                const int lr = mi * 16 + q * 4 + r;          // 0..63 in wave tile
                #pragma unroll
                for (int c = 0; c < NCLS; ++c)
                    pl[(wv * 64 + lr) * NCLS + c] = p[c];
            }
        }
    }
    __syncthreads();

    // combine wave pairs (0+2 -> rows 0..63, 1+3 -> rows 64..127), atomic out.
    for (int e = tid; e < BM * NCLS; e += 256) {
        const int lr = e / NCLS, c = e - lr * NCLS;
        float v;
        if (lr < 64) v = pl[(0 * 64 + lr)      * NCLS + c] + pl[(2 * 64 + lr)      * NCLS + c];
        else         v = pl[(1 * 64 + lr - 64) * NCLS + c] + pl[(3 * 64 + lr - 64) * NCLS + c];
        atomicAdd(out + (size_t)(bm + lr) * NCLS + c, v);
    }
}

// ---------------------------------------------------------------------------
extern "C" void kernel_launch(void* const* d_in, const int* in_sizes, int n_in,
                              void* d_out, int out_size, void* d_ws, size_t ws_size,
                              hipStream_t stream)
{
    const int*   x       = (const int*)d_in[0];
    const int*   lengths = (const int*)d_in[1];
    const float* emb     = (const float*)d_in[2];
    const float* W1      = (const float*)d_in[3];
    const float* b1      = (const float*)d_in[4];
    const float* W2      = (const float*)d_in[5];
    const float* b2      = (const float*)d_in[6];
    float*       out     = (float*)d_out;

    const int B = in_sizes[1];               // 4096

    unsigned short* rep = (unsigned short*)d_ws;          // [B][640]
    unsigned short* w1t = rep + (size_t)B * KPAD;         // [1024][640]
    unsigned short* w2t = w1t + (size_t)NPAD * KPAD;      // [5][1024]

    const int poolBlks = B / 2;                           // 2048
    const int outBlks  = (B * NCLS + 255) / 256;          // 80
    const int grid     = poolBlks + 640 + 20 + outBlks;   // 2788

    fused_prep_pool<<<grid, 256, 0, stream>>>(
        x, lengths, emb, W1, w1t, W2, w2t, b2, out, rep, B, poolBlks);

    dim3 g1(NPAD / BN, B / BM);              // (8, 32) = 256 blocks, 1/CU
    gemm1p<<<g1, 256, 0, stream>>>(rep, w1t, b1, w2t, out, B);
}

// Round 3
// 165.046 us; speedup vs baseline: 1.0124x; 1.0124x over previous
//
#include <hip/hip_runtime.h>
#include <float.h>
#include <stdint.h>

#define EMB_DIM  300
#define MAX_LEN  128
#define HIDDEN   1000
#define NCLS     5
#define VOCAB_SZ 50000
#define KPAD     640     // rep cols: avg -> [0,320), max -> [320,640)
#define NPAD     1024    // 1000 padded to 16*64
#define EMBPAD   320     // 300 dims padded to 320 shorts = 640 B = 40 x 16B chunks

typedef float    f32x4   __attribute__((ext_vector_type(4)));
typedef __bf16   bf16x8  __attribute__((ext_vector_type(8)));
typedef unsigned short ushort8v __attribute__((ext_vector_type(8)));

#define EMB_CHUNKS (VOCAB_SZ * (EMBPAD / 8))            // 2,000,000 chunks of 8 shorts
#define EMB_BLOCKS ((EMB_CHUNKS + 255) / 256)           // 7813

__device__ __forceinline__ unsigned short f2bf(float f) {
    union { float f; uint32_t u; } v; v.f = f;
    uint32_t u = v.u;
    return (unsigned short)((u + 0x7FFFu + ((u >> 16) & 1u)) >> 16);   // RNE
}
__device__ __forceinline__ float bf2f(unsigned short h) {
    union { uint32_t u; float f; } v; v.u = ((uint32_t)h) << 16;
    return v.f;
}

// ---------------------------------------------------------------------------
// prep_all: emb f32->bf16 table + W1T (with k-remap) + W2T + out=b2 init.
//  blocks [0, embBlocks):               emb -> embb bf16 [50000][320], pad dims = 0
//  blocks [embBlocks, +640):            W1T bf16 [1024][640]
//                                       k<300 -> W1 row k (avg), 320<=k<620 ->
//                                       W1 row k-20 (max), else 0
//  blocks [embBlocks+640, +20):         W2 -> W2T bf16 [5][1024]
//  blocks [embBlocks+660, +outBlocks):  out[m][c] = b2[c]  (gemm1p atomic-adds)
// ---------------------------------------------------------------------------
__global__ __launch_bounds__(256) void prep_all(
    const float* __restrict__ emb, unsigned short* __restrict__ embb,
    const float* __restrict__ W1, unsigned short* __restrict__ Bt,
    const float* __restrict__ W2, unsigned short* __restrict__ W2t,
    const float* __restrict__ b2, float* __restrict__ out,
    int M, int embBlocks)
{
    __shared__ float tsh[32][33];
    const int blk = blockIdx.x;
    const int tid = threadIdx.x;

    if (blk < embBlocks) {
        const int i = blk * 256 + tid;                // chunk of 8 shorts (16 B)
        if (i >= EMB_CHUNKS) return;
        const int v  = i / 40;
        const int ch = i - v * 40;
        ushort8v o = {0, 0, 0, 0, 0, 0, 0, 0};
        if (ch < 38) {                                // dims [ch*8, ch*8+8)
            const float* src = emb + (size_t)v * EMB_DIM + ch * 8;
            const float4 f0 = *(const float4*)src;    // row base 16B-aligned (1200 B rows)
            o[0] = f2bf(f0.x); o[1] = f2bf(f0.y); o[2] = f2bf(f0.z); o[3] = f2bf(f0.w);
            if (ch < 37) {
                const float4 f1 = *(const float4*)(src + 4);
                o[4] = f2bf(f1.x); o[5] = f2bf(f1.y); o[6] = f2bf(f1.z); o[7] = f2bf(f1.w);
            }                                         // ch==37: dims 300..303 stay 0
        }
        *(ushort8v*)(embb + (size_t)v * EMBPAD + ch * 8) = o;
        return;
    }
    const int pb = blk - embBlocks;
    if (pb < 640) {
        // W1T: pb -> (px, py) in (32 n-tiles, 20 k-tiles)
        const int px = pb & 31, py = pb >> 5;
        const int tx = tid & 31, ty = tid >> 5;        // 32 x 8
        const int n0 = px * 32, k0 = py * 32;
        #pragma unroll
        for (int i = 0; i < 4; ++i) {
            const int k = k0 + ty + i * 8, n = n0 + tx;
            // k-remap for the split rep layout
            const int r = (k < 300) ? k : ((k >= 320 && k < 620) ? (k - 20) : -1);
            tsh[ty + i * 8][tx] = (r >= 0 && n < HIDDEN) ? W1[(size_t)r * HIDDEN + n] : 0.f;
        }
        __syncthreads();
        #pragma unroll
        for (int i = 0; i < 4; ++i) {
            const int n = n0 + ty + i * 8, k = k0 + tx;
            Bt[(size_t)n * KPAD + k] = f2bf(tsh[tx][ty + i * 8]);
        }
        return;
    }
    const int pc = pb - 640;
    if (pc < 20) {                                    // W2T: 20 blocks
        const int i = pc * 256 + tid;                 // [0, 5120)
        const int c = i >> 10, k = i & 1023;
        const float v = (k < HIDDEN) ? W2[(size_t)k * NCLS + c] : 0.f;
        W2t[(size_t)c * 1024 + k] = f2bf(v);
        return;
    }
    const int po = pc - 20;                           // out init = b2
    const int oi = po * 256 + tid;
    if (oi < M * NCLS) out[oi] = b2[oi % NCLS];
}

// ---------------------------------------------------------------------------
// pool_w16: one WAVE per batch row; lanes 0..39 each own 8 dims and issue ONE
// 16 B load per index (vs round-1's two ragged 8 B wave-loads). 4 rows per
// 256-thread block, 4-deep load pipeline. Writes split layout:
// avg -> rep[b][0..320), max -> rep[b][320..640). Pad dims pooled from exact
// zeros in embb -> pooled pad cols are 0 against zero W1T columns.
// ---------------------------------------------------------------------------
__global__ __launch_bounds__(256) void pool_w16(
    const int* __restrict__ x, const int* __restrict__ lengths,
    const unsigned short* __restrict__ embb, unsigned short* __restrict__ rep)
{
    __shared__ int sidx[4 * MAX_LEN];
    const int blk = blockIdx.x;
    const int tid = threadIdx.x;

    {   // stage + clamp 512 indices with all 256 threads
        int v0 = x[blk * 512 + tid];
        int v1 = x[blk * 512 + tid + 256];
        sidx[tid]       = max(0, min(v0, VOCAB_SZ - 1));
        sidx[tid + 256] = max(0, min(v1, VOCAB_SZ - 1));
    }
    __syncthreads();

    const int w = tid >> 6;                 // wave -> row
    const int l = tid & 63;
    const int b = blk * 4 + w;

    int L = lengths[b];
    L = max(1, min(L, MAX_LEN));

    if (l >= 40) return;                    // 40 lanes x 16 B = 640 B row

    const int d = l * 8;                    // dims [d, d+8)
    const unsigned short* base = embb + d;
    const int* si = sidx + w * MAX_LEN;

    float s[8], mx[8];
    #pragma unroll
    for (int e = 0; e < 8; ++e) { s[e] = 0.f; mx[e] = -FLT_MAX; }

    int i = 0;
    for (; i + 4 <= L; i += 4) {            // 4 x 16 B in flight per wave
        const ushort8v u0 = *(const ushort8v*)(base + (size_t)si[i]     * EMBPAD);
        const ushort8v u1 = *(const ushort8v*)(base + (size_t)si[i + 1] * EMBPAD);
        const ushort8v u2 = *(const ushort8v*)(base + (size_t)si[i + 2] * EMBPAD);
        const ushort8v u3 = *(const ushort8v*)(base + (size_t)si[i + 3] * EMBPAD);
        #pragma unroll
        for (int e = 0; e < 8; ++e) {
            const float f0 = bf2f(u0[e]), f1 = bf2f(u1[e]);
            const float f2 = bf2f(u2[e]), f3 = bf2f(u3[e]);
            s[e]  += (f0 + f1) + (f2 + f3);
            mx[e]  = fmaxf(mx[e], fmaxf(fmaxf(f0, f1), fmaxf(f2, f3)));
        }
    }
    for (; i < L; ++i) {
        const ushort8v u = *(const ushort8v*)(base + (size_t)si[i] * EMBPAD);
        #pragma unroll
        for (int e = 0; e < 8; ++e) {
            const float f = bf2f(u[e]);
            s[e] += f;
            mx[e] = fmaxf(mx[e], f);
        }
    }

    const float inv = 1.0f / (float)L;
    ushort8v av, mv;
    #pragma unroll
    for (int e = 0; e < 8; ++e) { av[e] = f2bf(s[e] * inv); mv[e] = f2bf(mx[e]); }
    *(ushort8v*)(rep + (size_t)b * KPAD + d)       = av;   // avg -> [0,320)
    *(ushort8v*)(rep + (size_t)b * KPAD + 320 + d) = mv;   // max -> [320,640)
}

// ---------------------------------------------------------------------------
// pool_f32_fb (fallback if ws too small for the bf16 table) — same split
// rep layout, gathers f32 directly.
// ---------------------------------------------------------------------------
__global__ __launch_bounds__(128) void pool_f32_fb(
    const int* __restrict__ x, const int* __restrict__ lengths,
    const float* __restrict__ emb, unsigned short* __restrict__ rep)
{
    const int b = blockIdx.x;
    const int t = threadIdx.x;

    __shared__ int sidx[MAX_LEN];
    {
        int v = x[b * MAX_LEN + t];
        sidx[t] = max(0, min(v, VOCAB_SZ - 1));
    }
    __syncthreads();

    unsigned short* rb = rep + (size_t)b * KPAD;

    if (t >= 75) {
        if (t < 80) {                       // zero avg pad cols [300,320)
            ushort4 z = {0, 0, 0, 0};
            *(ushort4*)(rb + 300 + (t - 75) * 4) = z;
        } else if (t < 85) {                // zero max pad cols [620,640)
            ushort4 z = {0, 0, 0, 0};
            *(ushort4*)(rb + 620 + (t - 80) * 4) = z;
        }
        return;
    }

    int L = lengths[b];
    L = max(1, min(L, MAX_LEN));

    const int d = t * 4;
    const float* base = emb + d;
    float4 s  = {0.f, 0.f, 0.f, 0.f};
    float4 mx = {-FLT_MAX, -FLT_MAX, -FLT_MAX, -FLT_MAX};

    for (int i = 0; i < L; ++i) {
        const float4 a = *(const float4*)(base + (size_t)sidx[i] * EMB_DIM);
        s.x += a.x; s.y += a.y; s.z += a.z; s.w += a.w;
        mx.x = fmaxf(mx.x, a.x); mx.y = fmaxf(mx.y, a.y);
        mx.z = fmaxf(mx.z, a.z); mx.w = fmaxf(mx.w, a.w);
    }

    const float inv = 1.0f / (float)L;
    ushort4 av, mv;
    av.x = f2bf(s.x * inv); av.y = f2bf(s.y * inv);
    av.z = f2bf(s.z * inv); av.w = f2bf(s.w * inv);
    mv.x = f2bf(mx.x); mv.y = f2bf(mx.y); mv.z = f2bf(mx.z); mv.w = f2bf(mx.w);
    *(ushort4*)(rb + d)       = av;         // avg -> [0,300) of [0,320)
    *(ushort4*)(rb + 320 + d) = mv;         // max -> [320,620) of [320,640)
}

// ---------------------------------------------------------------------------
// gemm1p: out[m][c] += relu(rep@W1T + b1)[:, n-slice] @ W2 slice.
// 128x128 tile, BK=64 (10 K-iters), 4 waves x 64x64, 4x4 16x16x32 frags,
// LDS 64KB dbuf, global_load_lds(16B). Fused epilogue -> atomicAdd into out.
// ---------------------------------------------------------------------------
#define BM 128
#define BN 128
#define BK 64

__global__ __launch_bounds__(256, 2) void gemm1p(
    const unsigned short* __restrict__ A,    // rep  [M][640] bf16
    const unsigned short* __restrict__ Bt,   // W1T  [1024][640] bf16
    const float* __restrict__ bias,          // b1 [1000]
    const unsigned short* __restrict__ W2t,  // [5][1024] bf16
    float* __restrict__ out,                 // [M][5] f32, pre-init to b2
    int M)
{
    __shared__ unsigned short As[2][BM * BK];   // 16 KB per buffer
    __shared__ unsigned short Bs[2][BN * BK];

    const int tid  = threadIdx.x;
    const int wv   = tid >> 6;
    const int lane = tid & 63;
    const int bm   = blockIdx.y * BM;
    const int bn   = blockIdx.x * BN;
    const int wr   = (wv & 1) * 64;
    const int wc   = (wv >> 1) * 64;

    f32x4 acc[4][4] = {};

    auto stage = [&](int buf, int k0) {
        #pragma unroll
        for (int j = 0; j < 4; ++j) {
            const int ci  = (wv * 4 + j) * 64 + lane;
            const int row = ci >> 3, c = ci & 7;
            __builtin_amdgcn_global_load_lds(
                A + (size_t)(bm + row) * KPAD + k0 + c * 8,
                &As[buf][(wv * 4 + j) * 512], 16, 0, 0);
        }
        #pragma unroll
        for (int j = 0; j < 4; ++j) {
            const int ci  = (wv * 4 + j) * 64 + lane;
            const int row = ci >> 3, c = ci & 7;
            __builtin_amdgcn_global_load_lds(
                Bt + (size_t)(bn + row) * KPAD + k0 + c * 8,
                &Bs[buf][(wv * 4 + j) * 512], 16, 0, 0);
        }
    };

    stage(0, 0);
    int cur = 0;
    const int q = lane >> 4, r16 = lane & 15;

    #pragma unroll 1
    for (int it = 0; it < KPAD / BK; ++it) {
        __syncthreads();                           // drains prev stage
        if (it + 1 < KPAD / BK) stage(cur ^ 1, (it + 1) * BK);

        #pragma unroll
        for (int ks = 0; ks < BK; ks += 32) {
            bf16x8 af[4], bfr[4];
            #pragma unroll
            for (int mi = 0; mi < 4; ++mi)
                af[mi] = *(const bf16x8*)&As[cur][(wr + mi * 16 + r16) * BK + ks + q * 8];
            #pragma unroll
            for (int nj = 0; nj < 4; ++nj)
                bfr[nj] = *(const bf16x8*)&Bs[cur][(wc + nj * 16 + r16) * BK + ks + q * 8];
            #pragma unroll
            for (int mi = 0; mi < 4; ++mi)
                #pragma unroll
                for (int nj = 0; nj < 4; ++nj)
                    acc[mi][nj] = __builtin_amdgcn_mfma_f32_16x16x32_bf16(
                        af[mi], bfr[nj], acc[mi][nj], 0, 0, 0);
        }
        cur ^= 1;
    }

    // ---- fused epilogue: h -> partial logits ----
    float bv[4], w2v[4][NCLS];
    #pragma unroll
    for (int nj = 0; nj < 4; ++nj) {
        const int n = bn + wc + nj * 16 + r16;
        if (n < HIDDEN) {
            bv[nj] = bias[n];
            #pragma unroll
            for (int c = 0; c < NCLS; ++c) w2v[nj][c] = bf2f(W2t[c * 1024 + n]);
        } else {
            bv[nj] = 0.f;
            #pragma unroll
            for (int c = 0; c < NCLS; ++c) w2v[nj][c] = 0.f;
        }
    }

    __syncthreads();                     // LDS reuse: As becomes float scratch
    float* pl = (float*)As;              // [4 waves][64 rows][5]

    #pragma unroll
    for (int mi = 0; mi < 4; ++mi) {
        #pragma unroll
        for (int r = 0; r < 4; ++r) {
            float p[NCLS] = {0.f, 0.f, 0.f, 0.f, 0.f};
            #pragma unroll
            for (int nj = 0; nj < 4; ++nj) {
                float h = fmaxf(acc[mi][nj][r] + bv[nj], 0.f);
                #pragma unroll
                for (int c = 0; c < NCLS; ++c) p[c] += h * w2v[nj][c];
            }
            #pragma unroll
            for (int off = 1; off < 16; off <<= 1)
                #pragma unroll
                for (int c = 0; c < NCLS; ++c)
                    p[c] += __shfl_xor(p[c], off, 64);
            if (r16 == 0) {
                const int lr = mi * 16 + q * 4 + r;
                #pragma unroll
                for (int c = 0; c < NCLS; ++c)
                    pl[(wv * 64 + lr) * NCLS + c] = p[c];
            }
        }
    }
    __syncthreads();

    for (int e = tid; e < BM * NCLS; e += 256) {
        const int lr = e / NCLS, c = e - lr * NCLS;
        float v;
        if (lr < 64) v = pl[(0 * 64 + lr)      * NCLS + c] + pl[(2 * 64 + lr)      * NCLS + c];
        else         v = pl[(1 * 64 + lr - 64) * NCLS + c] + pl[(3 * 64 + lr - 64) * NCLS + c];
        atomicAdd(out + (size_t)(bm + lr) * NCLS + c, v);
    }
}

// ---------------------------------------------------------------------------
extern "C" void kernel_launch(void* const* d_in, const int* in_sizes, int n_in,
                              void* d_out, int out_size, void* d_ws, size_t ws_size,
                              hipStream_t stream)
{
    const int*   x       = (const int*)d_in[0];
    const int*   lengths = (const int*)d_in[1];
    const float* emb     = (const float*)d_in[2];
    const float* W1      = (const float*)d_in[3];
    const float* b1      = (const float*)d_in[4];
    const float* W2      = (const float*)d_in[5];
    const float* b2      = (const float*)d_in[6];
    float*       out     = (float*)d_out;

    const int B = in_sizes[1];               // 4096

    unsigned short* rep  = (unsigned short*)d_ws;         // [B][640]
    unsigned short* w1t  = rep + (size_t)B * KPAD;        // [1024][640]
    unsigned short* w2t  = w1t + (size_t)NPAD * KPAD;     // [5][1024]
    unsigned short* embb = w2t + (size_t)NCLS * 1024;     // [50000][320]

    const size_t need = ((size_t)B * KPAD + (size_t)NPAD * KPAD + NCLS * 1024
                         + (size_t)VOCAB_SZ * EMBPAD) * 2;

    const bool useBf16 = (ws_size >= need);
    const int  embBlks = useBf16 ? EMB_BLOCKS : 0;
    const int  outBlks = (B * NCLS + 255) / 256;

    prep_all<<<embBlks + 660 + outBlks, 256, 0, stream>>>(
        emb, embb, W1, w1t, W2, w2t, b2, out, B, embBlks);

    if (useBf16) {
        pool_w16<<<B / 4, 256, 0, stream>>>(x, lengths, embb, rep);
    } else {
        pool_f32_fb<<<B, 128, 0, stream>>>(x, lengths, emb, rep);
    }

    dim3 g1(NPAD / BN, B / BM);              // (8, 32) = 256 blocks
    gemm1p<<<g1, 256, 0, stream>>>(rep, w1t, b1, w2t, out, B);
}

// Round 4
// 161.326 us; speedup vs baseline: 1.0358x; 1.0231x over previous
//
#include <hip/hip_runtime.h>
#include <float.h>
#include <stdint.h>

#define EMB_DIM  300
#define MAX_LEN  128
#define HIDDEN   1000
#define NCLS     5
#define VOCAB_SZ 50000
#define KPAD     640     // 600 padded to 10*64
#define NPAD     1024    // 1000 padded to 16*64
#define EMBPAD   320     // 300 dims padded to 320 shorts = 640 B

typedef float    f32x4   __attribute__((ext_vector_type(4)));
typedef __bf16   bf16x8  __attribute__((ext_vector_type(8)));
typedef unsigned short ushort8v __attribute__((ext_vector_type(8)));

#define EMB_CHUNKS (VOCAB_SZ * (EMBPAD / 8))            // 2,000,000 chunks of 8 shorts
#define EMB_BLOCKS ((EMB_CHUNKS + 255) / 256)           // 7813

__device__ __forceinline__ unsigned short f2bf(float f) {
    union { float f; uint32_t u; } v; v.f = f;
    uint32_t u = v.u;
    return (unsigned short)((u + 0x7FFFu + ((u >> 16) & 1u)) >> 16);   // RNE
}
__device__ __forceinline__ float bf2f(unsigned short h) {
    union { uint32_t u; float f; } v; v.u = ((uint32_t)h) << 16;
    return v.f;
}

// ---------------------------------------------------------------------------
// prep_all: emb f32->bf16 table + W1T + W2T + out=b2 init. (round-1 proven)
//  blocks [0, embBlocks):               emb -> embb bf16 [50000][320]
//  blocks [embBlocks, +640):            transpose W1 -> W1T bf16 [1024][640]
//  blocks [embBlocks+640, +20):         W2 -> W2T bf16 [5][1024]
//  blocks [embBlocks+660, +outBlocks):  out[m][c] = b2[c]  (gemm1p atomic-adds)
// ---------------------------------------------------------------------------
__global__ __launch_bounds__(256) void prep_all(
    const float* __restrict__ emb, unsigned short* __restrict__ embb,
    const float* __restrict__ W1, unsigned short* __restrict__ Bt,
    const float* __restrict__ W2, unsigned short* __restrict__ W2t,
    const float* __restrict__ b2, float* __restrict__ out,
    int M, int embBlocks)
{
    __shared__ float tsh[32][33];
    const int blk = blockIdx.x;
    const int tid = threadIdx.x;

    if (blk < embBlocks) {
        const int i = blk * 256 + tid;                // chunk of 8 shorts (16 B)
        if (i >= EMB_CHUNKS) return;
        const int v  = i / 40;
        const int ch = i - v * 40;
        ushort8v o = {0, 0, 0, 0, 0, 0, 0, 0};
        if (ch < 38) {                                // dims [ch*8, ch*8+8)
            const float* src = emb + (size_t)v * EMB_DIM + ch * 8;
            const float4 f0 = *(const float4*)src;    // row base 16B-aligned (1200 B rows)
            o[0] = f2bf(f0.x); o[1] = f2bf(f0.y); o[2] = f2bf(f0.z); o[3] = f2bf(f0.w);
            if (ch < 37) {
                const float4 f1 = *(const float4*)(src + 4);
                o[4] = f2bf(f1.x); o[5] = f2bf(f1.y); o[6] = f2bf(f1.z); o[7] = f2bf(f1.w);
            }                                         // ch==37: dims 300..303 stay 0
        }
        *(ushort8v*)(embb + (size_t)v * EMBPAD + ch * 8) = o;
        return;
    }
    const int pb = blk - embBlocks;
    if (pb < 640) {
        // W1 transpose: pb -> (px, py) in (32 n-tiles, 20 k-tiles)
        const int px = pb & 31, py = pb >> 5;
        const int tx = tid & 31, ty = tid >> 5;        // 32 x 8
        const int n0 = px * 32, k0 = py * 32;
        #pragma unroll
        for (int i = 0; i < 4; ++i) {
            const int k = k0 + ty + i * 8, n = n0 + tx;
            tsh[ty + i * 8][tx] = (k < 600 && n < HIDDEN) ? W1[(size_t)k * HIDDEN + n] : 0.f;
        }
        __syncthreads();
        #pragma unroll
        for (int i = 0; i < 4; ++i) {
            const int n = n0 + ty + i * 8, k = k0 + tx;
            Bt[(size_t)n * KPAD + k] = f2bf(tsh[tx][ty + i * 8]);
        }
        return;
    }
    const int pc = pb - 640;
    if (pc < 20) {                                    // W2T: 20 blocks
        const int i = pc * 256 + tid;                 // [0, 5120)
        const int c = i >> 10, k = i & 1023;
        const float v = (k < HIDDEN) ? W2[(size_t)k * NCLS + c] : 0.f;
        W2t[(size_t)c * 1024 + k] = f2bf(v);
        return;
    }
    const int po = pc - 20;                           // out init = b2
    const int oi = po * 256 + tid;
    if (oi < M * NCLS) out[oi] = b2[oi % NCLS];
}

// ---------------------------------------------------------------------------
// pool_bf16: gather + masked avg/max over bf16 table -> rep bf16 [B][640].
// Round-1 proven config (128 thr/block, 1 row/block, ushort4/lane) plus:
// pre-clamped indices at staging, 4-deep unrolled gather.
// Layout: avg -> [0,300), max -> [300,600), zeros [600,640).
// ---------------------------------------------------------------------------
__global__ __launch_bounds__(128) void pool_bf16(
    const int* __restrict__ x, const int* __restrict__ lengths,
    const unsigned short* __restrict__ embb, unsigned short* __restrict__ rep)
{
    const int b = blockIdx.x;
    const int t = threadIdx.x;

    __shared__ int sidx[MAX_LEN];
    {
        int v = x[b * MAX_LEN + t];
        sidx[t] = max(0, min(v, VOCAB_SZ - 1));
    }
    __syncthreads();

    unsigned short* rb = rep + (size_t)b * KPAD;

    if (t >= 75) {
        if (t < 85) {                      // zero pad cols 600..639
            ushort4 z = {0, 0, 0, 0};
            *(ushort4*)(rb + 600 + (t - 75) * 4) = z;
        }
        return;
    }

    int L = lengths[b];
    L = max(1, min(L, MAX_LEN));

    const int d = t * 4;
    const unsigned short* base = embb + d;
    float4 s  = {0.f, 0.f, 0.f, 0.f};
    float4 mx = {-FLT_MAX, -FLT_MAX, -FLT_MAX, -FLT_MAX};

    int i = 0;
    for (; i + 4 <= L; i += 4) {           // 4 loads in flight
        const ushort4 u0 = *(const ushort4*)(base + (size_t)sidx[i]     * EMBPAD);
        const ushort4 u1 = *(const ushort4*)(base + (size_t)sidx[i + 1] * EMBPAD);
        const ushort4 u2 = *(const ushort4*)(base + (size_t)sidx[i + 2] * EMBPAD);
        const ushort4 u3 = *(const ushort4*)(base + (size_t)sidx[i + 3] * EMBPAD);
        const float a0 = bf2f(u0.x), a1 = bf2f(u0.y), a2 = bf2f(u0.z), a3 = bf2f(u0.w);
        const float b0 = bf2f(u1.x), b1 = bf2f(u1.y), b2v = bf2f(u1.z), b3 = bf2f(u1.w);
        const float c0 = bf2f(u2.x), c1 = bf2f(u2.y), c2 = bf2f(u2.z), c3 = bf2f(u2.w);
        const float e0 = bf2f(u3.x), e1 = bf2f(u3.y), e2 = bf2f(u3.z), e3 = bf2f(u3.w);
        s.x += (a0 + b0) + (c0 + e0);
        s.y += (a1 + b1) + (c1 + e1);
        s.z += (a2 + b2v) + (c2 + e2);
        s.w += (a3 + b3) + (c3 + e3);
        mx.x = fmaxf(mx.x, fmaxf(fmaxf(a0, b0), fmaxf(c0, e0)));
        mx.y = fmaxf(mx.y, fmaxf(fmaxf(a1, b1), fmaxf(c1, e1)));
        mx.z = fmaxf(mx.z, fmaxf(fmaxf(a2, b2v), fmaxf(c2, e2)));
        mx.w = fmaxf(mx.w, fmaxf(fmaxf(a3, b3), fmaxf(c3, e3)));
    }
    for (; i < L; ++i) {
        const ushort4 u = *(const ushort4*)(base + (size_t)sidx[i] * EMBPAD);
        const float a0 = bf2f(u.x), a1 = bf2f(u.y), a2 = bf2f(u.z), a3 = bf2f(u.w);
        s.x += a0; s.y += a1; s.z += a2; s.w += a3;
        mx.x = fmaxf(mx.x, a0); mx.y = fmaxf(mx.y, a1);
        mx.z = fmaxf(mx.z, a2); mx.w = fmaxf(mx.w, a3);
    }

    const float inv = 1.0f / (float)L;
    ushort4 av, mv;
    av.x = f2bf(s.x * inv); av.y = f2bf(s.y * inv);
    av.z = f2bf(s.z * inv); av.w = f2bf(s.w * inv);
    mv.x = f2bf(mx.x); mv.y = f2bf(mx.y); mv.z = f2bf(mx.z); mv.w = f2bf(mx.w);
    *(ushort4*)(rb + d)       = av;     // avg -> [0,300)
    *(ushort4*)(rb + 300 + d) = mv;     // max -> [300,600)
}

// ---------------------------------------------------------------------------
// pool_f32 (fallback if ws too small for the bf16 table).
// ---------------------------------------------------------------------------
__global__ __launch_bounds__(128) void pool_f32(
    const int* __restrict__ x, const int* __restrict__ lengths,
    const float* __restrict__ emb, unsigned short* __restrict__ rep)
{
    const int b = blockIdx.x;
    const int t = threadIdx.x;

    __shared__ int sidx[MAX_LEN];
    {
        int v = x[b * MAX_LEN + t];
        sidx[t] = max(0, min(v, VOCAB_SZ - 1));
    }
    __syncthreads();

    unsigned short* rb = rep + (size_t)b * KPAD;

    if (t >= 75) {
        if (t < 85) {
            ushort4 z = {0, 0, 0, 0};
            *(ushort4*)(rb + 600 + (t - 75) * 4) = z;
        }
        return;
    }

    int L = lengths[b];
    L = max(1, min(L, MAX_LEN));

    const int d = t * 4;
    const float* base = emb + d;
    float4 s  = {0.f, 0.f, 0.f, 0.f};
    float4 mx = {-FLT_MAX, -FLT_MAX, -FLT_MAX, -FLT_MAX};

    for (int i = 0; i < L; ++i) {
        const float4 a = *(const float4*)(base + (size_t)sidx[i] * EMB_DIM);
        s.x += a.x; s.y += a.y; s.z += a.z; s.w += a.w;
        mx.x = fmaxf(mx.x, a.x); mx.y = fmaxf(mx.y, a.y);
        mx.z = fmaxf(mx.z, a.z); mx.w = fmaxf(mx.w, a.w);
    }

    const float inv = 1.0f / (float)L;
    ushort4 av, mv;
    av.x = f2bf(s.x * inv); av.y = f2bf(s.y * inv);
    av.z = f2bf(s.z * inv); av.w = f2bf(s.w * inv);
    mv.x = f2bf(mx.x); mv.y = f2bf(mx.y); mv.z = f2bf(mx.z); mv.w = f2bf(mx.w);
    *(ushort4*)(rb + d)       = av;
    *(ushort4*)(rb + 300 + d) = mv;
}

// ---------------------------------------------------------------------------
// gemm1p: out[m][c] += relu(rep@W1T + b1)[:, n-slice] @ W2 slice.
// 128x128 tile, BK=64 (10 K-iters), 4 waves x 64x64, 4x4 16x16x32 frags,
// LDS 64KB dbuf, global_load_lds(16B). Fused epilogue -> atomicAdd into out
// (pre-initialized to b2 by prep_all).
// ---------------------------------------------------------------------------
#define BM 128
#define BN 128
#define BK 64

__global__ __launch_bounds__(256, 2) void gemm1p(
    const unsigned short* __restrict__ A,    // rep  [M][640] bf16
    const unsigned short* __restrict__ Bt,   // W1T  [1024][640] bf16
    const float* __restrict__ bias,          // b1 [1000]
    const unsigned short* __restrict__ W2t,  // [5][1024] bf16
    float* __restrict__ out,                 // [M][5] f32, pre-init to b2
    int M)
{
    __shared__ unsigned short As[2][BM * BK];   // 16 KB per buffer
    __shared__ unsigned short Bs[2][BN * BK];

    const int tid  = threadIdx.x;
    const int wv   = tid >> 6;
    const int lane = tid & 63;
    const int bm   = blockIdx.y * BM;
    const int bn   = blockIdx.x * BN;
    const int wr   = (wv & 1) * 64;
    const int wc   = (wv >> 1) * 64;

    f32x4 acc[4][4] = {};

    auto stage = [&](int buf, int k0) {
        #pragma unroll
        for (int j = 0; j < 4; ++j) {
            const int ci  = (wv * 4 + j) * 64 + lane;
            const int row = ci >> 3, c = ci & 7;
            __builtin_amdgcn_global_load_lds(
                A + (size_t)(bm + row) * KPAD + k0 + c * 8,
                &As[buf][(wv * 4 + j) * 512], 16, 0, 0);
        }
        #pragma unroll
        for (int j = 0; j < 4; ++j) {
            const int ci  = (wv * 4 + j) * 64 + lane;
            const int row = ci >> 3, c = ci & 7;
            __builtin_amdgcn_global_load_lds(
                Bt + (size_t)(bn + row) * KPAD + k0 + c * 8,
                &Bs[buf][(wv * 4 + j) * 512], 16, 0, 0);
        }
    };

    stage(0, 0);
    int cur = 0;
    const int q = lane >> 4, r16 = lane & 15;

    #pragma unroll 1
    for (int it = 0; it < KPAD / BK; ++it) {
        __syncthreads();                           // drains prev stage
        if (it + 1 < KPAD / BK) stage(cur ^ 1, (it + 1) * BK);

        #pragma unroll
        for (int ks = 0; ks < BK; ks += 32) {
            bf16x8 af[4], bfr[4];
            #pragma unroll
            for (int mi = 0; mi < 4; ++mi)
                af[mi] = *(const bf16x8*)&As[cur][(wr + mi * 16 + r16) * BK + ks + q * 8];
            #pragma unroll
            for (int nj = 0; nj < 4; ++nj)
                bfr[nj] = *(const bf16x8*)&Bs[cur][(wc + nj * 16 + r16) * BK + ks + q * 8];
            #pragma unroll
            for (int mi = 0; mi < 4; ++mi)
                #pragma unroll
                for (int nj = 0; nj < 4; ++nj)
                    acc[mi][nj] = __builtin_amdgcn_mfma_f32_16x16x32_bf16(
                        af[mi], bfr[nj], acc[mi][nj], 0, 0, 0);
        }
        cur ^= 1;
    }

    // ---- fused epilogue: h -> partial logits ----
    // C/D layout: col(n) = r16, row(m) = q*4 + reg (+ mi*16).
    float bv[4], w2v[4][NCLS];
    #pragma unroll
    for (int nj = 0; nj < 4; ++nj) {
        const int n = bn + wc + nj * 16 + r16;
        if (n < HIDDEN) {
            bv[nj] = bias[n];
            #pragma unroll
            for (int c = 0; c < NCLS; ++c) w2v[nj][c] = bf2f(W2t[c * 1024 + n]);
        } else {
            bv[nj] = 0.f;
            #pragma unroll
            for (int c = 0; c < NCLS; ++c) w2v[nj][c] = 0.f;
        }
    }

    __syncthreads();                     // LDS reuse: As becomes float scratch
    float* pl = (float*)As;              // [4 waves][64 rows][5]

    #pragma unroll
    for (int mi = 0; mi < 4; ++mi) {
        #pragma unroll
        for (int r = 0; r < 4; ++r) {
            float p[NCLS] = {0.f, 0.f, 0.f, 0.f, 0.f};
            #pragma unroll
            for (int nj = 0; nj < 4; ++nj) {
                float h = fmaxf(acc[mi][nj][r] + bv[nj], 0.f);
                #pragma unroll
                for (int c = 0; c < NCLS; ++c) p[c] += h * w2v[nj][c];
            }
            #pragma unroll
            for (int off = 1; off < 16; off <<= 1)
                #pragma unroll
                for (int c = 0; c < NCLS; ++c)
                    p[c] += __shfl_xor(p[c], off, 64);
            if (r16 == 0) {
                const int lr = mi * 16 + q * 4 + r;
                #pragma unroll
                for (int c = 0; c < NCLS; ++c)
                    pl[(wv * 64 + lr) * NCLS + c] = p[c];
            }
        }
    }
    __syncthreads();

    for (int e = tid; e < BM * NCLS; e += 256) {
        const int lr = e / NCLS, c = e - lr * NCLS;
        float v;
        if (lr < 64) v = pl[(0 * 64 + lr)      * NCLS + c] + pl[(2 * 64 + lr)      * NCLS + c];
        else         v = pl[(1 * 64 + lr - 64) * NCLS + c] + pl[(3 * 64 + lr - 64) * NCLS + c];
        atomicAdd(out + (size_t)(bm + lr) * NCLS + c, v);
    }
}

// ---------------------------------------------------------------------------
extern "C" void kernel_launch(void* const* d_in, const int* in_sizes, int n_in,
                              void* d_out, int out_size, void* d_ws, size_t ws_size,
                              hipStream_t stream)
{
    const int*   x       = (const int*)d_in[0];
    const int*   lengths = (const int*)d_in[1];
    const float* emb     = (const float*)d_in[2];
    const float* W1      = (const float*)d_in[3];
    const float* b1      = (const float*)d_in[4];
    const float* W2      = (const float*)d_in[5];
    const float* b2      = (const float*)d_in[6];
    float*       out     = (float*)d_out;

    const int B = in_sizes[1];               // 4096

    unsigned short* rep  = (unsigned short*)d_ws;         // [B][640]
    unsigned short* w1t  = rep + (size_t)B * KPAD;        // [1024][640]
    unsigned short* w2t  = w1t + (size_t)NPAD * KPAD;     // [5][1024]
    unsigned short* embb = w2t + (size_t)NCLS * 1024;     // [50000][320]

    const size_t need = ((size_t)B * KPAD + (size_t)NPAD * KPAD + NCLS * 1024
                         + (size_t)VOCAB_SZ * EMBPAD) * 2;

    const bool useBf16 = (ws_size >= need);
    const int  embBlks = useBf16 ? EMB_BLOCKS : 0;
    const int  outBlks = (B * NCLS + 255) / 256;

    prep_all<<<embBlks + 660 + outBlks, 256, 0, stream>>>(
        emb, embb, W1, w1t, W2, w2t, b2, out, B, embBlks);

    if (useBf16) {
        pool_bf16<<<B, 128, 0, stream>>>(x, lengths, embb, rep);
    } else {
        pool_f32<<<B, 128, 0, stream>>>(x, lengths, emb, rep);
    }

    dim3 g1(NPAD / BN, B / BM);              // (8, 32) = 256 blocks
    gemm1p<<<g1, 256, 0, stream>>>(rep, w1t, b1, w2t, out, B);
}